// Round 6
// baseline (313.393 us; speedup 1.0000x reference)
//
#include <hip/hip_runtime.h>
#include <hip/hip_bf16.h>

// ===================== Round 14: split-K 4 — TLP latency hiding ================
// R13 post-mortem: barrier-free/LDS-free loop REGRESSED (122->170us) while all
// pipes dropped (MfmaUtil 7%) -> latency-bound, not sync-bound. Little's law:
// ~200B in flight/wave x 10.5 waves/CU (grid-limited: 1280 blocks = 5/CU) =
// ~2KB/CU -> ~2TB/s effective; need ~3x. VGPR=64 & LDS=0 allow 32 waves/CU.
// Fix: split-K 2->4 (grid 2560 = 10 blocks/CU -> 8 resident = 32 waves/CU).
// kc ranges even (24 each) + guarded kc=96 tail on kidx=3; kc=97 skipped
// (W zero-pad). XCD swizzle keeps all 20 blocks of an mt on one XCD.
// Atomics double (4 partials/out) but stay XCD-local. Loop body unchanged.
// Predicted: occupancy 33->65-85%, gemm 170->75-95us, FETCH ~140-165MB,
// total ~150-175us. If gemm >=120 at high occupancy: pivot to traffic
// reduction (bf16 X prepass) / issue-rate analysis.

#define NFFT   512
#define HOP    128
#define KDIM   3084      // 257*6*2
#define KP     3136      // K padded (49*64)
#define NOUT   600
#define NP     640       // W rows padded (5*128)
#define BM     64
#define BN     128

#define NFRAG_K 98       // KP/32 k-chunks
#define FRAG_SH 512      // shorts per fragment (64 lanes x 8)
#define WTOT    ((size_t)(NP / 16) * NFRAG_K * FRAG_SH)  // 4.01 MB
#define NKSPLIT 4        // split-K factor
#define GRIDB   (128 * 5 * NKSPLIT)   // 2560

typedef short s16x8 __attribute__((ext_vector_type(8)));
typedef float f32x4 __attribute__((ext_vector_type(4)));

static __device__ __forceinline__ unsigned short bf16_bits(float f) {
    __hip_bfloat16 b = __float2bfloat16(f);   // RNE - R4-verified path
    return *(unsigned short*)&b;
}

static __device__ __forceinline__ s16x8 cvt_frag(float4 lo, float4 hi) {
    s16x8 r;
    r[0] = (short)bf16_bits(lo.x); r[1] = (short)bf16_bits(lo.y);
    r[2] = (short)bf16_bits(lo.z); r[3] = (short)bf16_bits(lo.w);
    r[4] = (short)bf16_bits(hi.x); r[5] = (short)bf16_bits(hi.y);
    r[6] = (short)bf16_bits(hi.z); r[7] = (short)bf16_bits(hi.w);
    return r;
}

// ---------------- W generation (fragment layout) + out zeroing ---------------
// Fragment (n16, kc) holds W[n16*16 + (l&15)][kc*32 + (l>>4)*8 + e] at
// shorts offset ((n16*98 + kc)*64 + l)*8 + e. Row n is block l's rowbuf.
// (unchanged from R11/R13 — passed)
__global__ __launch_bounds__(256) void gen_W(unsigned short* __restrict__ Wt,
                                             float4* __restrict__ outZ,
                                             int nvec4) {
    __shared__ float costab[512];
    __shared__ __align__(16) unsigned short rowbuf[KP];   // 6272 B
    const int l   = blockIdx.x;     // 0..639  (row n = l)
    const int tid = threadIdx.x;
    const float w0 = 6.283185307179586f / 512.0f;

    // zero the output buffer in-kernel (replaces the SDMA memset)
    for (int i = blockIdx.x * 256 + tid; i < nvec4; i += NP * 256)
        outZ[i] = make_float4(0.f, 0.f, 0.f, 0.f);

    *(int4*)(rowbuf + tid * 8) = make_int4(0, 0, 0, 0);
    if (tid < 136) *(int4*)(rowbuf + (256 + tid) * 8) = make_int4(0, 0, 0, 0);
    costab[tid]       = __cosf((float)tid * w0);
    costab[tid + 256] = __cosf((float)(tid + 256) * w0);
    __syncthreads();

    if (l < NOUT) {
        const int p = l + 256;
        float env = 0.0f;
#pragma unroll
        for (int tt = 0; tt < 6; ++tt) {
            int m = p - HOP * tt;
            if (m >= 0 && m < NFFT) {
                float w = 0.5f - 0.5f * costab[m];
                env += w * w;
            }
        }
        const float inv = 1.0f / (512.0f * env);
        for (int f = tid; f <= 256; f += 256) {
            float cf = (f == 0 || f == 256) ? 1.0f : 2.0f;
#pragma unroll
            for (int t = 0; t < 6; ++t) {
                int n = p - HOP * t;
                if (n >= 0 && n < NFFT) {
                    float w = 0.5f - 0.5f * costab[n];
                    float scale = cf * w * inv;
                    int a = (f * n) & 511;
                    float c = costab[a];
                    float s = costab[(a + 384) & 511];
                    rowbuf[f * 12 + t * 2 + 0] = bf16_bits(scale * c);
                    rowbuf[f * 12 + t * 2 + 1] = bf16_bits(-scale * s);
                }
            }
        }
    }
    __syncthreads();

    // scatter row n=l into fragment layout: 392 units of 16B (kc 0..97, q 0..3)
    const int n16 = l >> 4, r = l & 15;
    for (int u = tid; u < 392; u += 256) {
        const int kc = u >> 2, q = u & 3;
        int4 val = *(const int4*)(rowbuf + kc * 32 + q * 8);
        *(int4*)(Wt + (((size_t)n16 * NFRAG_K + kc) * 64 + q * 16 + r) * 8) = val;
    }
}

// ---------------- GEMM: out += X * W^T (split-K = 4) -------------------------
// 256 thr = 4 waves, wave tile 32(m) x 64(n); grid 2560 = 128mt x 5nt x 4k.
// No LDS, no barriers: A fragments loaded per-wave straight from X (fp32),
// converted in-register; B fragments direct from pre-swizzled W. 2-deep
// named register double-buffer, kc (K=32) granularity. TLP via 8 blocks/CU.
__global__ __launch_bounds__(256, 4) void gemm_kernel(
        const float* __restrict__ X,           // fp32 [8192][3084]
        const unsigned short* __restrict__ Wt, // bf16 frags, WTOT shorts
        float* __restrict__ out) {             // fp32 [8192][600], pre-zeroed
    const int tid = threadIdx.x;
    // XCD swizzle: the 20 blocks (5 nt x 4 kidx) of one mt share an XCD.
    const int bid  = blockIdx.x;           // 0..2559
    const int xcd  = bid & 7;
    const int rest = bid >> 3;             // 0..319
    const int mt   = xcd * 16 + rest / 20; // 0..127
    const int sub  = rest % 20;
    const int nt   = sub >> 2;             // 0..4
    const int kidx = sub & 3;              // 0..3
    const int mBase = mt * BM;
    const int nBase = nt * BN;

    const int lane = tid & 63;
    const int wave = tid >> 6;
    const int wm   = (wave & 1) * 32;
    const int wn   = (wave >> 1) * 64;
    const int lrow = lane & 15;
    const int quad = lane >> 4;

    // A fragment rows for this lane (two 16-row groups of the wave's 32 rows)
    const float* aRow0 = X + (size_t)(mBase + wm + lrow) * KDIM;
    const float* aRow1 = aRow0 + (size_t)16 * KDIM;
    const int kq = quad * 8;               // lane's k-octet within a kc chunk

    // B fragment base for this wave: n16 row-block = nt*8 + (wave>>1)*4 + j
    const int n16base = nt * 8 + (wave >> 1) * 4;
    const unsigned short* wB0 = Wt + (size_t)n16base * NFRAG_K * FRAG_SH
                                   + (size_t)lane * 8;

    f32x4 acc[2][4];
#pragma unroll
    for (int i = 0; i < 2; ++i)
#pragma unroll
        for (int j = 0; j < 4; ++j) acc[i][j] = (f32x4){0.f, 0.f, 0.f, 0.f};

#define LOADA(L0, H0, L1, H1, kc_)                                             \
    {                                                                          \
        const int kb_ = (kc_) * 32 + kq;                                       \
        L0 = *(const float4*)(aRow0 + kb_);                                    \
        H0 = *(const float4*)(aRow0 + kb_ + 4);                                \
        L1 = *(const float4*)(aRow1 + kb_);                                    \
        H1 = *(const float4*)(aRow1 + kb_ + 4);                                \
    }

#define LOADB(BV, kc_)                                                         \
    {                                                                          \
        _Pragma("unroll")                                                      \
        for (int j = 0; j < 4; ++j)                                            \
            BV[j] = *(const s16x8*)(const void*)(wB0 +                         \
                        ((size_t)j * NFRAG_K + (size_t)(kc_)) * FRAG_SH);      \
    }

#define COMPUTE(L0, H0, L1, H1, BV)                                            \
    {                                                                          \
        s16x8 af0 = cvt_frag(L0, H0);                                          \
        s16x8 af1 = cvt_frag(L1, H1);                                          \
        _Pragma("unroll")                                                      \
        for (int j = 0; j < 4; ++j)                                            \
            acc[0][j] = __builtin_amdgcn_mfma_f32_16x16x32_bf16(               \
                af0, BV[j], acc[0][j], 0, 0, 0);                               \
        _Pragma("unroll")                                                      \
        for (int j = 0; j < 4; ++j)                                            \
            acc[1][j] = __builtin_amdgcn_mfma_f32_16x16x32_bf16(               \
                af1, BV[j], acc[1][j], 0, 0, 0);                               \
    }

    // kc ranges (even lengths of 24): kidx*24 .. kidx*24+24; kidx=3 adds the
    // guarded kc=96 tail. kc=97 skipped: W pad rows are all-zero there.
    const int kcBeg = kidx * 24;
    const int kcEnd = kcBeg + 24;

    float4 a0l0, a0h0, a1l0, a1h0;        // set0 (named regs, rule #20)
    float4 a0l1, a0h1, a1l1, a1h1;        // set1
    s16x8  bv0[4], bv1[4];

    LOADA(a0l0, a0h0, a1l0, a1h0, kcBeg);
    LOADB(bv0, kcBeg);
    for (int kc = kcBeg; kc + 1 < kcEnd; kc += 2) {
        LOADA(a0l1, a0h1, a1l1, a1h1, kc + 1);
        LOADB(bv1, kc + 1);
        COMPUTE(a0l0, a0h0, a1l0, a1h0, bv0);
        if (kc + 2 < kcEnd) {
            LOADA(a0l0, a0h0, a1l0, a1h0, kc + 2);
            LOADB(bv0, kc + 2);
        }
        COMPUTE(a0l1, a0h1, a1l1, a1h1, bv1);
    }

    if (kidx == 3) {
        // kc = 96: k in [3072,3104) crosses KDIM=3084 -> per-element guard.
        const int kb = 96 * 32 + kq;
        float e0[8], e1[8];
#pragma unroll
        for (int e = 0; e < 8; ++e) {
            const int k = kb + e;
            const bool ok = (k < KDIM);
            e0[e] = ok ? aRow0[k] : 0.f;
            e1[e] = ok ? aRow1[k] : 0.f;
        }
        float4 l0 = make_float4(e0[0], e0[1], e0[2], e0[3]);
        float4 h0 = make_float4(e0[4], e0[5], e0[6], e0[7]);
        float4 l1 = make_float4(e1[0], e1[1], e1[2], e1[3]);
        float4 h1 = make_float4(e1[4], e1[5], e1[6], e1[7]);
        LOADB(bv0, 96);
        COMPUTE(l0, h0, l1, h1, bv0);
    }

#undef LOADA
#undef LOADB
#undef COMPUTE

    // ---- epilogue: H1 layout (n=lane&15, m=quad*4+reg), atomic accumulate
#pragma unroll
    for (int i = 0; i < 2; ++i) {
#pragma unroll
        for (int j = 0; j < 4; ++j) {
            int gn = nBase + wn + j * 16 + lrow;
            if (gn < NOUT) {
#pragma unroll
                for (int r = 0; r < 4; ++r) {
                    int gm = mBase + wm + i * 16 + quad * 4 + r;
                    atomicAdd(out + (size_t)gm * NOUT + gn, acc[i][j][r]);
                }
            }
        }
    }
}

extern "C" void kernel_launch(void* const* d_in, const int* in_sizes, int n_in,
                              void* d_out, int out_size, void* d_ws, size_t ws_size,
                              hipStream_t stream) {
    const float* X = (const float*)d_in[0];
    unsigned short* W = (unsigned short*)d_ws;   // bf16 fragment layout, 4.01 MB
    float* out = (float*)d_out;

    gen_W<<<dim3(NP), 256, 0, stream>>>(W, (float4*)d_out, out_size / 4);
    gemm_kernel<<<dim3(GRIDB), 256, 0, stream>>>(X, W, out);
}

// Round 9
// 237.345 us; speedup vs baseline: 1.3204x; 1.3204x over previous
//
#include <hip/hip_runtime.h>
#include <hip/hip_bf16.h>

// ===================== Round 17: DMA staging, __syncthreads-only sync ==========
// R15/R16 both died with "container failed twice" (no counters); R11-family
// kernels run fine. The un-auditable risk in R15/R16 was the hand-counted
// vmcnt + raw s_barrier protocol -> deleted entirely. Same hypothesis as R15
// (R11's limiter is the staging critical path: vmcnt-wait(A regs)->cvt->
// ds_write->barrier each step), tested with ONLY standard sync:
//   iter t: DMA(t+1) -> other buf (global_load_lds, no VGPR round-trip)
//           COMPUTE tile t (A: ds_read fp32 + cvt->bf16; B: regs, R11's
//           consume-then-reload pattern), __syncthreads().
// The __syncthreads drain (vmcnt0+lgkm0+barrier) IS the DMA completion
// guarantee + buffer release; only the residual latency after ~400-800cy of
// compute remains exposed. No inline asm, no counted waits, no raw barriers.
// A fp32 in LDS with rule-21 XOR slot swizzle (inverse on global source,
// forward on read; <=2-way verified). B/geometry/split-K/tail/epilogue/gen_W
// = proven R11 code. Single-variable experiment vs R11.
// Predicted: LDS 32768, FETCH ~105MB, MfmaUtil 15-25%, gemm 122->70-95us,
// absmax 0.001953125. Container fails again => global_load_lds condemned.

#define NFFT   512
#define HOP    128
#define KDIM   3084      // 257*6*2
#define KP     3136      // K padded (49*64)
#define NOUT   600
#define NP     640       // W rows padded (5*128)
#define BM     64
#define BN     128
#define NTILES 24        // DMA K-tiles per block (64 k each); 2*24*64 = 3072

#define NFRAG_K 98       // KP/32 k-chunks
#define FRAG_SH 512      // shorts per fragment (64 lanes x 8)
#define WTOT    ((size_t)(NP / 16) * NFRAG_K * FRAG_SH)  // 4.01 MB
#define GRIDB   (128 * 5 * 2)   // 1280

typedef short s16x8 __attribute__((ext_vector_type(8)));
typedef float f32x4 __attribute__((ext_vector_type(4)));

static __device__ __forceinline__ unsigned short bf16_bits(float f) {
    __hip_bfloat16 b = __float2bfloat16(f);   // RNE - R4-verified path
    return *(unsigned short*)&b;
}

static __device__ __forceinline__ s16x8 cvt_frag(float4 lo, float4 hi) {
    s16x8 r;
    r[0] = (short)bf16_bits(lo.x); r[1] = (short)bf16_bits(lo.y);
    r[2] = (short)bf16_bits(lo.z); r[3] = (short)bf16_bits(lo.w);
    r[4] = (short)bf16_bits(hi.x); r[5] = (short)bf16_bits(hi.y);
    r[6] = (short)bf16_bits(hi.z); r[7] = (short)bf16_bits(hi.w);
    return r;
}

// async global->LDS DMA, 16B per lane, dest = wave-uniform base + lane*16
static __device__ __forceinline__ void gload_lds16(const void* g, void* l) {
    __builtin_amdgcn_global_load_lds(
        (const __attribute__((address_space(1))) unsigned int*)g,
        (__attribute__((address_space(3))) unsigned int*)l, 16, 0, 0);
}

// ---------------- W generation (fragment layout) + out zeroing ---------------
// Fragment (n16, kc) holds W[n16*16 + (l&15)][kc*32 + (l>>4)*8 + e] at
// shorts offset ((n16*98 + kc)*64 + l)*8 + e. (unchanged — passed R11/R13/R14)
__global__ __launch_bounds__(256) void gen_W(unsigned short* __restrict__ Wt,
                                             float4* __restrict__ outZ,
                                             int nvec4) {
    __shared__ float costab[512];
    __shared__ __align__(16) unsigned short rowbuf[KP];   // 6272 B
    const int l   = blockIdx.x;     // 0..639  (row n = l)
    const int tid = threadIdx.x;
    const float w0 = 6.283185307179586f / 512.0f;

    // zero the output buffer in-kernel (replaces the SDMA memset)
    for (int i = blockIdx.x * 256 + tid; i < nvec4; i += NP * 256)
        outZ[i] = make_float4(0.f, 0.f, 0.f, 0.f);

    *(int4*)(rowbuf + tid * 8) = make_int4(0, 0, 0, 0);
    if (tid < 136) *(int4*)(rowbuf + (256 + tid) * 8) = make_int4(0, 0, 0, 0);
    costab[tid]       = __cosf((float)tid * w0);
    costab[tid + 256] = __cosf((float)(tid + 256) * w0);
    __syncthreads();

    if (l < NOUT) {
        const int p = l + 256;
        float env = 0.0f;
#pragma unroll
        for (int tt = 0; tt < 6; ++tt) {
            int m = p - HOP * tt;
            if (m >= 0 && m < NFFT) {
                float w = 0.5f - 0.5f * costab[m];
                env += w * w;
            }
        }
        const float inv = 1.0f / (512.0f * env);
        for (int f = tid; f <= 256; f += 256) {
            float cf = (f == 0 || f == 256) ? 1.0f : 2.0f;
#pragma unroll
            for (int t = 0; t < 6; ++t) {
                int n = p - HOP * t;
                if (n >= 0 && n < NFFT) {
                    float w = 0.5f - 0.5f * costab[n];
                    float scale = cf * w * inv;
                    int a = (f * n) & 511;
                    float c = costab[a];
                    float s = costab[(a + 384) & 511];
                    rowbuf[f * 12 + t * 2 + 0] = bf16_bits(scale * c);
                    rowbuf[f * 12 + t * 2 + 1] = bf16_bits(-scale * s);
                }
            }
        }
    }
    __syncthreads();

    const int n16 = l >> 4, r = l & 15;
    for (int u = tid; u < 392; u += 256) {
        const int kc = u >> 2, q = u & 3;
        int4 val = *(const int4*)(rowbuf + kc * 32 + q * 8);
        *(int4*)(Wt + (((size_t)n16 * NFRAG_K + kc) * 64 + q * 16 + r) * 8) = val;
    }
}

// ---------------- GEMM: out += X * W^T (split-K = 2) -------------------------
// 256 thr = 4 waves, wave tile 32(m) x 64(n); grid 1280 = 128mt x 5nt x 2k.
// A: fp32 DMA'd to double-buffered LDS via global_load_lds; XOR slot swizzle
// (slot ^= row&7) on the GLOBAL source and the LDS read; bf16 cvt at read.
// B: direct global->reg from pre-swizzled W (R11 pattern). One __syncthreads
// per tile does ALL synchronization (DMA completion + buffer release).
__global__ __launch_bounds__(256, 4) void gemm_kernel(
        const float* __restrict__ X,           // fp32 [8192][3084]
        const unsigned short* __restrict__ Wt, // bf16 frags, WTOT shorts
        float* __restrict__ out) {             // fp32 [8192][600], pre-zeroed
    // A tile buffers: [2][64 rows][16 slots of 16B] fp32, 16 KB each
    __shared__ __align__(16) float As[2][4096];

    const int tid = threadIdx.x;
    const int bid  = blockIdx.x;           // 0..1279
    const int xcd  = bid & 7;
    const int rest = bid >> 3;             // 0..159
    const int mt   = xcd * 16 + rest / 10; // 0..127
    const int sub  = rest % 10;
    const int nt   = sub >> 1;             // 0..4
    const int kidx = sub & 1;              // 0/1
    const int mBase = mt * BM;
    const int nBase = nt * BN;
    const int gBeg  = kidx * NTILES;       // tile index base (64 k per tile)

    const int lane = tid & 63;
    const int wave = tid >> 6;
    const int wm   = (wave & 1) * 32;
    const int wn   = (wave >> 1) * 64;
    const int lrow = lane & 15;
    const int quad = lane >> 4;

    // ---- DMA source map (inverse-swizzled): unit u, lane l carries logical
    // (row = u*16 + wave*4 + (l>>4), slot = (l&15) ^ (row&7)) into physical
    // slot l&15 of that row (linear dest = DMA hardware requirement).
    const int rQ  = wave * 4 + (lane >> 4);        // row base (u adds 16)
    const int sLg = (lane & 15) ^ (rQ & 7);        // u*16 keeps row&7
    const float* dmaSrc = X + (size_t)(mBase + rQ) * KDIM + sLg * 4;
    char* ldsB0 = (char*)&As[0][0];
    char* ldsB1 = (char*)&As[1][0];

#define DMA_TILE(LB, g_)                                                       \
    {                                                                          \
        const float* s_ = dmaSrc + (size_t)(g_) * 64;                          \
        _Pragma("unroll")                                                      \
        for (int u = 0; u < 4; ++u)                                            \
            gload_lds16(s_ + (size_t)u * 16 * KDIM,                            \
                        (LB) + u * 4096 + wave * 1024);                        \
    }

    // B fragment base for this wave: n16 row-block = nt*8 + (wave>>1)*4 + j
    const int n16base = nt * 8 + (wave >> 1) * 4;
    const unsigned short* wB0 = Wt + (size_t)n16base * NFRAG_K * FRAG_SH
                                   + (size_t)lane * 8;

#define LOADB(BV, kc_)                                                         \
    {                                                                          \
        _Pragma("unroll")                                                      \
        for (int j = 0; j < 4; ++j)                                            \
            BV[j] = *(const s16x8*)(const void*)(wB0 +                         \
                        ((size_t)j * NFRAG_K + (size_t)(kc_)) * FRAG_SH);      \
    }

    f32x4 acc[2][4];
#pragma unroll
    for (int i = 0; i < 2; ++i)
#pragma unroll
        for (int j = 0; j < 4; ++j) acc[i][j] = (f32x4){0.f, 0.f, 0.f, 0.f};

    // read one A fragment from LDS (swizzled slots) and convert to bf16
#define AFRAG(AF, LB, i16, ks)                                                 \
    {                                                                          \
        const int R_  = wm + (i16) * 16 + lrow;                                \
        const int sp_ = (ks) * 8 + quad * 2;                                   \
        const int x_  = R_ & 7;                                                \
        float4 f0_ = *(const float4*)((LB) + R_ * 256 + ((sp_)     ^ x_) * 16);\
        float4 f1_ = *(const float4*)((LB) + R_ * 256 + ((sp_ + 1) ^ x_) * 16);\
        AF = cvt_frag(f0_, f1_);                                               \
    }

#define COMPUTE_KS(LB, ks, BV)                                                 \
    {                                                                          \
        s16x8 af0, af1;                                                        \
        AFRAG(af0, LB, 0, ks);                                                 \
        AFRAG(af1, LB, 1, ks);                                                 \
        _Pragma("unroll")                                                      \
        for (int j = 0; j < 4; ++j)                                            \
            acc[0][j] = __builtin_amdgcn_mfma_f32_16x16x32_bf16(               \
                af0, BV[j], acc[0][j], 0, 0, 0);                               \
        _Pragma("unroll")                                                      \
        for (int j = 0; j < 4; ++j)                                            \
            acc[1][j] = __builtin_amdgcn_mfma_f32_16x16x32_bf16(               \
                af1, BV[j], acc[1][j], 0, 0, 0);                               \
    }

    // ---- prologue: DMA tile 0 into buf0, prefetch B(0); sync drains DMA(0).
    s16x8 bv0[4], bv1[4];
    DMA_TILE(ldsB0, gBeg);
    LOADB(bv0, 2 * gBeg);
    LOADB(bv1, 2 * gBeg + 1);
    __syncthreads();

    for (int t = 0; t < NTILES; ++t) {
        const int g = gBeg + t;
        char* LB = (t & 1) ? ldsB1 : ldsB0;   // compute from this buffer
        char* LN = (t & 1) ? ldsB0 : ldsB1;   // DMA next tile into the other
        if (t + 1 < NTILES) DMA_TILE(LN, g + 1);   // flies under compute
        COMPUTE_KS(LB, 0, bv0);
        if (t + 1 < NTILES) LOADB(bv0, 2 * (g + 1));       // reload after use
        COMPUTE_KS(LB, 1, bv1);
        if (t + 1 < NTILES) LOADB(bv1, 2 * (g + 1) + 1);
        __syncthreads();   // drains DMA(t+1) + B(t+1); releases LB. Only sync.
    }

    // ---- K tail: kc = 96 (k 3072..3103, guard vs KDIM=3084), kidx==1 only.
    // Register path, identical to R13/R14 (passed twice). kc=97: W is zero.
    if (kidx) {
        const float* aRow0 = X + (size_t)(mBase + wm + lrow) * KDIM;
        const float* aRow1 = aRow0 + (size_t)16 * KDIM;
        const int kb = 96 * 32 + quad * 8;
        float e0[8], e1[8];
#pragma unroll
        for (int e = 0; e < 8; ++e) {
            const int k = kb + e;
            const bool ok = (k < KDIM);
            e0[e] = ok ? aRow0[k] : 0.f;
            e1[e] = ok ? aRow1[k] : 0.f;
        }
        float4 l0 = make_float4(e0[0], e0[1], e0[2], e0[3]);
        float4 h0 = make_float4(e0[4], e0[5], e0[6], e0[7]);
        float4 l1 = make_float4(e1[0], e1[1], e1[2], e1[3]);
        float4 h1 = make_float4(e1[4], e1[5], e1[6], e1[7]);
        LOADB(bv0, 96);
        s16x8 af0 = cvt_frag(l0, h0);
        s16x8 af1 = cvt_frag(l1, h1);
#pragma unroll
        for (int j = 0; j < 4; ++j)
            acc[0][j] = __builtin_amdgcn_mfma_f32_16x16x32_bf16(
                af0, bv0[j], acc[0][j], 0, 0, 0);
#pragma unroll
        for (int j = 0; j < 4; ++j)
            acc[1][j] = __builtin_amdgcn_mfma_f32_16x16x32_bf16(
                af1, bv0[j], acc[1][j], 0, 0, 0);
    }

#undef DMA_TILE
#undef LOADB
#undef AFRAG
#undef COMPUTE_KS

    // ---- epilogue: H1 layout (n=lane&15, m=quad*4+reg), atomic accumulate
#pragma unroll
    for (int i = 0; i < 2; ++i) {
#pragma unroll
        for (int j = 0; j < 4; ++j) {
            int gn = nBase + wn + j * 16 + lrow;
            if (gn < NOUT) {
#pragma unroll
                for (int r = 0; r < 4; ++r) {
                    int gm = mBase + wm + i * 16 + quad * 4 + r;
                    atomicAdd(out + (size_t)gm * NOUT + gn, acc[i][j][r]);
                }
            }
        }
    }
}

extern "C" void kernel_launch(void* const* d_in, const int* in_sizes, int n_in,
                              void* d_out, int out_size, void* d_ws, size_t ws_size,
                              hipStream_t stream) {
    const float* X = (const float*)d_in[0];
    unsigned short* W = (unsigned short*)d_ws;   // bf16 fragment layout, 4.01 MB
    float* out = (float*)d_out;

    gen_W<<<dim3(NP), 256, 0, stream>>>(W, (float4*)d_out, out_size / 4);
    gemm_kernel<<<dim3(GRIDB), 256, 0, stream>>>(X, W, out);
}

// Round 10
// 228.530 us; speedup vs baseline: 1.3713x; 1.0386x over previous
//
#include <hip/hip_runtime.h>
#include <hip/hip_bf16.h>

// ===================== Round 18: BK=256 — long steps, no split-K, no atomics ===
// R17 post-mortem: FIVE different staging/sync structures all land at 118-124us
// (DMA+syncthreads == reg-staged == lgkm-barrier); reg-only is worse. Per-CU:
// 120 step-periods in 123us = ~2460 cy/step vs ~350 cy of work -> every
// variant exposes ~1 latency round per SHORT step. The unturned knob: step
// LENGTH. BK 64->256: 12 tiles, compute window ~1500-2000cy > load latency,
// so R11's reg-staged prefetch (issued one full step ahead, survives the
// lgkm-only barrier) arrives before its wait. Steps per CU 120->30.
// Split-K removed (grid 640 = 128mt x 5nt): each output owned by ONE block ->
// plain stores, atomics + pre-zeroing deleted. LDS 2x33.8KB -> 2 blocks/CU.
// All component code (pack path, barrier, B reload, W layout, kc=96 tail,
// XCD swizzle) is the verified R11/R17 code with constants widened.
// Predicted: gemm 123->40-65us, MfmaUtil 20-35%, WRITE 38->20MB, FETCH
// ~105MB, LDS 67584, VGPR ~170-200 (bounds 256,2). absmax ~0.00195
// (2 atomic partials -> 1 sequential sum; inside bf16 noise).

#define NFFT   512
#define HOP    128
#define KDIM   3084      // 257*6*2
#define KP     3136      // K padded (49*64) — W layout only
#define NOUT   600
#define NP     640       // W rows padded (5*128)
#define BM     64
#define BN     128
#define BK     256
#define KTILES 12        // 12*256 = 3072; k 3072..3083 via kc=96 tail
#define LDA2   264       // LDS row stride in shorts (256+8)
#define ABUF   (64 * LDA2)  // shorts per A buffer (16896)

#define NFRAG_K 98       // KP/32 k-chunks
#define FRAG_SH 512      // shorts per fragment (64 lanes x 8)
#define WTOT    ((size_t)(NP / 16) * NFRAG_K * FRAG_SH)  // 4.01 MB
#define GRIDB   (128 * 5)   // 640

typedef short s16x8 __attribute__((ext_vector_type(8)));
typedef float f32x4 __attribute__((ext_vector_type(4)));

static __device__ __forceinline__ unsigned short bf16_bits(float f) {
    __hip_bfloat16 b = __float2bfloat16(f);   // RNE - R4-verified path
    return *(unsigned short*)&b;
}

// LDS-only barrier: lgkmcnt(0) + s_barrier (proven R9-R11). Global loads stay
// in flight across it; ds ops complete before it.
static __device__ __forceinline__ void lds_barrier() {
    asm volatile("s_waitcnt lgkmcnt(0)" ::: "memory");
    __builtin_amdgcn_s_barrier();
    asm volatile("" ::: "memory");
}

// ---------------- W generation (fragment layout) -----------------------------
// Fragment (n16, kc) holds W[n16*16 + (l&15)][kc*32 + (l>>4)*8 + e] at
// shorts offset ((n16*98 + kc)*64 + l)*8 + e. (unchanged; zero-pass removed —
// plain-store epilogue overwrites every output element.)
__global__ __launch_bounds__(256) void gen_W(unsigned short* __restrict__ Wt) {
    __shared__ float costab[512];
    __shared__ __align__(16) unsigned short rowbuf[KP];   // 6272 B
    const int l   = blockIdx.x;     // 0..639  (row n = l)
    const int tid = threadIdx.x;
    const float w0 = 6.283185307179586f / 512.0f;

    *(int4*)(rowbuf + tid * 8) = make_int4(0, 0, 0, 0);
    if (tid < 136) *(int4*)(rowbuf + (256 + tid) * 8) = make_int4(0, 0, 0, 0);
    costab[tid]       = __cosf((float)tid * w0);
    costab[tid + 256] = __cosf((float)(tid + 256) * w0);
    __syncthreads();

    if (l < NOUT) {
        const int p = l + 256;
        float env = 0.0f;
#pragma unroll
        for (int tt = 0; tt < 6; ++tt) {
            int m = p - HOP * tt;
            if (m >= 0 && m < NFFT) {
                float w = 0.5f - 0.5f * costab[m];
                env += w * w;
            }
        }
        const float inv = 1.0f / (512.0f * env);
        for (int f = tid; f <= 256; f += 256) {
            float cf = (f == 0 || f == 256) ? 1.0f : 2.0f;
#pragma unroll
            for (int t = 0; t < 6; ++t) {
                int n = p - HOP * t;
                if (n >= 0 && n < NFFT) {
                    float w = 0.5f - 0.5f * costab[n];
                    float scale = cf * w * inv;
                    int a = (f * n) & 511;
                    float c = costab[a];
                    float s = costab[(a + 384) & 511];
                    rowbuf[f * 12 + t * 2 + 0] = bf16_bits(scale * c);
                    rowbuf[f * 12 + t * 2 + 1] = bf16_bits(-scale * s);
                }
            }
        }
    }
    __syncthreads();

    const int n16 = l >> 4, r = l & 15;
    for (int u = tid; u < 392; u += 256) {
        const int kc = u >> 2, q = u & 3;
        int4 val = *(const int4*)(rowbuf + kc * 32 + q * 8);
        *(int4*)(Wt + (((size_t)n16 * NFRAG_K + kc) * 64 + q * 16 + r) * 8) = val;
    }
}

// ---------------- GEMM: out = X * W^T (no split-K) ---------------------------
// 256 thr = 4 waves, wave tile 32(m) x 64(n); grid 640 = 128mt x 5nt.
// A: fp32 global -> regs (16 float4/thread, issued ONE FULL TILE ahead) ->
// bf16 pack -> double-buffered LDS; lgkm-only barrier per tile (prefetch
// survives). B: direct global->reg, 2-deep consume-then-reload. 12 tiles of
// K=256 (64 MFMA each) + guarded kc=96 register tail. Plain-store epilogue.
__global__ __launch_bounds__(256, 2) void gemm_kernel(
        const float* __restrict__ X,           // fp32 [8192][3084]
        const unsigned short* __restrict__ Wt, // bf16 frags, WTOT shorts
        float* __restrict__ out) {             // fp32 [8192][600]
    __shared__ __align__(16) unsigned short As[2 * ABUF];  // 67584 B

    const int tid = threadIdx.x;
    // XCD swizzle: the 5 nt-blocks of one mt share an XCD (X reuse in L2).
    const int bid  = blockIdx.x;           // 0..639
    const int xcd  = bid & 7;
    const int rest = bid >> 3;             // 0..79
    const int mt   = xcd * 16 + rest / 5;  // 0..127
    const int nt   = rest % 5;             // 0..4
    const int mBase = mt * BM;
    const int nBase = nt * BN;

    const int lane = tid & 63;
    const int wave = tid >> 6;
    const int wm   = (wave & 1) * 32;
    const int wn   = (wave >> 1) * 64;
    const int lrow = lane & 15;
    const int quad = lane >> 4;

    // A staging map: unit (p,c) p,c in 0..3 -> row = (tid>>4)+16p,
    // k-in-tile = c*64 + (tid&15)*4. Max k = 11*256+3*64+63 = 3071 < KDIM.
    const int aRowS = tid >> 4, aU = tid & 15;
    const float* aPtr = X + (size_t)(mBase + aRowS) * KDIM + aU * 4;

    // B fragment base for this wave: n16 row-block = nt*8 + (wave>>1)*4 + j
    const int n16base = nt * 8 + (wave >> 1) * 4;
    const unsigned short* wB0 = Wt + (size_t)n16base * NFRAG_K * FRAG_SH
                                   + (size_t)lane * 8;

#define ISSUE_A(s)                                                             \
    {                                                                          \
        const float* b_ = aPtr + (size_t)(s) * BK;                             \
        _Pragma("unroll")                                                      \
        for (int p = 0; p < 4; ++p)                                            \
            _Pragma("unroll")                                                  \
            for (int c = 0; c < 4; ++c)                                        \
                avH[p * 4 + c] =                                               \
                    *(const float4*)(b_ + (size_t)p * 16 * KDIM + c * 64);     \
    }

#define STAGE_A(AB)                                                            \
    {                                                                          \
        _Pragma("unroll")                                                      \
        for (int p = 0; p < 4; ++p)                                            \
            _Pragma("unroll")                                                  \
            for (int c = 0; c < 4; ++c) {                                      \
                float4 v = avH[p * 4 + c];                                     \
                unsigned long long pk = (unsigned long long)bf16_bits(v.x) |   \
                                    ((unsigned long long)bf16_bits(v.y) << 16) |\
                                    ((unsigned long long)bf16_bits(v.z) << 32) |\
                                    ((unsigned long long)bf16_bits(v.w) << 48); \
                *(unsigned long long*)(As + (AB) + (aRowS + 16 * p) * LDA2 +   \
                                       c * 64 + aU * 4) = pk;                  \
            }                                                                  \
    }

#define LOADB(BV, kc_)                                                         \
    {                                                                          \
        _Pragma("unroll")                                                      \
        for (int j = 0; j < 4; ++j)                                            \
            BV[j] = *(const s16x8*)(const void*)(wB0 +                         \
                        ((size_t)j * NFRAG_K + (size_t)(kc_)) * FRAG_SH);      \
    }

#define COMPUTE_KS(AB, ks, BV)                                                 \
    {                                                                          \
        const int koff = (ks) * 32 + quad * 8;                                 \
        s16x8 afr0 = *(const s16x8*)(const void*)(As + (AB) +                  \
                         (wm + lrow) * LDA2 + koff);                           \
        s16x8 afr1 = *(const s16x8*)(const void*)(As + (AB) +                  \
                         (wm + 16 + lrow) * LDA2 + koff);                      \
        _Pragma("unroll")                                                      \
        for (int j = 0; j < 4; ++j)                                            \
            acc[0][j] = __builtin_amdgcn_mfma_f32_16x16x32_bf16(               \
                afr0, BV[j], acc[0][j], 0, 0, 0);                              \
        _Pragma("unroll")                                                      \
        for (int j = 0; j < 4; ++j)                                            \
            acc[1][j] = __builtin_amdgcn_mfma_f32_16x16x32_bf16(               \
                afr1, BV[j], acc[1][j], 0, 0, 0);                              \
    }

// consume bv0/bv1 for (ksA, ksB) of tile t_, reload 2 kc ahead (max 97 < 98)
#define KS_PAIR(AB, t_, ksA, ksB)                                             \
    COMPUTE_KS(AB, ksA, bv0);                                                 \
    LOADB(bv0, 8 * (t_) + (ksA) + 2);                                         \
    COMPUTE_KS(AB, ksB, bv1);                                                 \
    LOADB(bv1, 8 * (t_) + (ksB) + 2);

    f32x4 acc[2][4];
#pragma unroll
    for (int i = 0; i < 2; ++i)
#pragma unroll
        for (int j = 0; j < 4; ++j) acc[i][j] = (f32x4){0.f, 0.f, 0.f, 0.f};

    float4 avH[16];          // staging prefetch (indices compile-time constant)
    s16x8  bv0[4], bv1[4];

    // ---- prologue: stage tile 0 into buf0; issue tile-1 loads; B(0),B(1)
    ISSUE_A(0);
    STAGE_A(0);              // counted vmcnt via register deps
    ISSUE_A(1);              // one full tile-period of prefetch distance
    LOADB(bv0, 0);
    LOADB(bv1, 1);
    lds_barrier();

    int ard = 0;
    for (int t = 0; t < KTILES; ++t) {
        const int awr = ard ^ ABUF;
        if (t + 1 < KTILES) {
            STAGE_A(awr);                      // waits only on avH's loads
            if (t + 2 < KTILES) ISSUE_A(t + 2);
        }
        KS_PAIR(ard, t, 0, 1)
        KS_PAIR(ard, t, 2, 3)
        KS_PAIR(ard, t, 4, 5)
        KS_PAIR(ard, t, 6, 7)
        lds_barrier();        // writes visible + reads complete; one per tile
        ard = awr;
    }

    // ---- K tail: kc = 96 (k 3072..3103, guard vs KDIM=3084), all blocks.
    {
        const float* aRow0 = X + (size_t)(mBase + wm + lrow) * KDIM;
        const float* aRow1 = aRow0 + (size_t)16 * KDIM;
        const int kb = 96 * 32 + quad * 8;
        float e0[8], e1[8];
#pragma unroll
        for (int e = 0; e < 8; ++e) {
            const int k = kb + e;
            const bool ok = (k < KDIM);
            e0[e] = ok ? aRow0[k] : 0.f;
            e1[e] = ok ? aRow1[k] : 0.f;
        }
        LOADB(bv0, 96);
        s16x8 af0, af1;
        af0[0] = (short)bf16_bits(e0[0]); af0[1] = (short)bf16_bits(e0[1]);
        af0[2] = (short)bf16_bits(e0[2]); af0[3] = (short)bf16_bits(e0[3]);
        af0[4] = (short)bf16_bits(e0[4]); af0[5] = (short)bf16_bits(e0[5]);
        af0[6] = (short)bf16_bits(e0[6]); af0[7] = (short)bf16_bits(e0[7]);
        af1[0] = (short)bf16_bits(e1[0]); af1[1] = (short)bf16_bits(e1[1]);
        af1[2] = (short)bf16_bits(e1[2]); af1[3] = (short)bf16_bits(e1[3]);
        af1[4] = (short)bf16_bits(e1[4]); af1[5] = (short)bf16_bits(e1[5]);
        af1[6] = (short)bf16_bits(e1[6]); af1[7] = (short)bf16_bits(e1[7]);
#pragma unroll
        for (int j = 0; j < 4; ++j)
            acc[0][j] = __builtin_amdgcn_mfma_f32_16x16x32_bf16(
                af0, bv0[j], acc[0][j], 0, 0, 0);
#pragma unroll
        for (int j = 0; j < 4; ++j)
            acc[1][j] = __builtin_amdgcn_mfma_f32_16x16x32_bf16(
                af1, bv0[j], acc[1][j], 0, 0, 0);
    }

#undef ISSUE_A
#undef STAGE_A
#undef LOADB
#undef COMPUTE_KS
#undef KS_PAIR

    // ---- epilogue: H1 layout (n=lane&15, m=quad*4+reg); each output owned
    // by exactly one block -> plain stores, no atomics, no pre-zeroing.
#pragma unroll
    for (int i = 0; i < 2; ++i) {
#pragma unroll
        for (int j = 0; j < 4; ++j) {
            int gn = nBase + wn + j * 16 + lrow;
            if (gn < NOUT) {
#pragma unroll
                for (int r = 0; r < 4; ++r) {
                    int gm = mBase + wm + i * 16 + quad * 4 + r;
                    out[(size_t)gm * NOUT + gn] = acc[i][j][r];
                }
            }
        }
    }
}

extern "C" void kernel_launch(void* const* d_in, const int* in_sizes, int n_in,
                              void* d_out, int out_size, void* d_ws, size_t ws_size,
                              hipStream_t stream) {
    const float* X = (const float*)d_in[0];
    unsigned short* W = (unsigned short*)d_ws;   // bf16 fragment layout, 4.01 MB
    float* out = (float*)d_out;

    gen_W<<<dim3(NP), 256, 0, stream>>>(W);
    gemm_kernel<<<dim3(GRIDB), 256, 0, stream>>>(X, W, out);
}